// Round 2
// baseline (974.745 us; speedup 1.0000x reference)
//
#include <hip/hip_runtime.h>
#include <hip/hip_bf16.h>

typedef __attribute__((ext_vector_type(8))) __bf16 bx8;
typedef __attribute__((ext_vector_type(4))) float  fx4;

// ---------------------------------------------------------------------------
// Problem constants: x [8192,1024], memory/read_w/write_w [8192,1024],
// biases [8192]. B*S = 8192 rows, M = 8192 slots, H = 1024.
// ---------------------------------------------------------------------------
#define ROWS 8192   // B*S
#define HID  1024
#define MEMN 8192

// ---------------------------------------------------------------------------
// fp32 -> bf16 elementwise convert (vectorized, exact grid: n = blocks*256*8)
// ---------------------------------------------------------------------------
__global__ __launch_bounds__(256)
void f32_to_bf16_vec(const float* __restrict__ in, __bf16* __restrict__ out)
{
    const size_t i = ((size_t)blockIdx.x * 256 + threadIdx.x) * 8;
    fx4 a = *(const fx4*)(in + i);
    fx4 b = *(const fx4*)(in + i + 4);
    bx8 u;
    u[0] = (__bf16)a[0]; u[1] = (__bf16)a[1]; u[2] = (__bf16)a[2]; u[3] = (__bf16)a[3];
    u[4] = (__bf16)b[0]; u[5] = (__bf16)b[1]; u[6] = (__bf16)b[2]; u[7] = (__bf16)b[3];
    *(bx8*)(out + i) = u;
}

// ---------------------------------------------------------------------------
// fp32 [R][C] -> bf16 [C][R] transpose (64x64 tiles via LDS)
// ---------------------------------------------------------------------------
__global__ __launch_bounds__(256)
void transpose_f32_to_bf16(const float* __restrict__ in, __bf16* __restrict__ out,
                           int R, int C)
{
    __shared__ float t[64][65];
    const int tid = threadIdx.x;
    const int r0 = blockIdx.y * 64;
    const int c0 = blockIdx.x * 64;
    const int lr = tid >> 4;          // 0..15
    const int lc = (tid & 15) * 4;    // 0..60
#pragma unroll
    for (int p = 0; p < 4; ++p) {
        const int rr = p * 16 + lr;
        const fx4 v = *(const fx4*)(in + (size_t)(r0 + rr) * C + c0 + lc);
        t[rr][lc + 0] = v[0]; t[rr][lc + 1] = v[1];
        t[rr][lc + 2] = v[2]; t[rr][lc + 3] = v[3];
    }
    __syncthreads();
    const int oc = tid >> 2;          // output row within tile = input col, 0..63
    const int ob = (tid & 3) * 16;    // input-row base, 0/16/32/48
    bx8 u0, u1;
#pragma unroll
    for (int j = 0; j < 8; ++j) {
        u0[j] = (__bf16)t[ob + j][oc];
        u1[j] = (__bf16)t[ob + 8 + j][oc];
    }
    *(bx8*)(out + (size_t)(c0 + oc) * R + r0 + ob)     = u0;
    *(bx8*)(out + (size_t)(c0 + oc) * R + r0 + ob + 8) = u1;
}

// ---------------------------------------------------------------------------
// In-place transpose of square bf16 matrix W [MEMN][MEMN], 64x64 tile pairs.
// Block (bj,bi) with bi<=bj loads tiles (bi,bj) and (bj,bi), writes each the
// other's transpose. Diagonal blocks: both point at the same tile; each
// address is written (twice) by the SAME thread with the same value — safe.
// ---------------------------------------------------------------------------
__global__ __launch_bounds__(256)
void transpose_inplace_bf16(__bf16* __restrict__ W)
{
    const int bi = blockIdx.y;
    const int bj = blockIdx.x;
    if (bi > bj) return;
    __shared__ __bf16 ta[64][72];
    __shared__ __bf16 tb[64][72];
    const int tid = threadIdx.x;
    const int lr = tid >> 3;          // 0..31
    const int lc = (tid & 7) * 8;     // 0..56
    const size_t N = MEMN;
    __bf16* At = W + (size_t)bi * 64 * N + (size_t)bj * 64;
    __bf16* Bt = W + (size_t)bj * 64 * N + (size_t)bi * 64;
#pragma unroll
    for (int p = 0; p < 2; ++p) {
        const int rr = p * 32 + lr;
        *(bx8*)(&ta[rr][lc]) = *(const bx8*)(At + (size_t)rr * N + lc);
        *(bx8*)(&tb[rr][lc]) = *(const bx8*)(Bt + (size_t)rr * N + lc);
    }
    __syncthreads();
    const int oc = tid >> 2;          // 0..63
    const int ob = (tid & 3) * 16;    // 0/16/32/48
    bx8 u0, u1, v0, v1;
#pragma unroll
    for (int j = 0; j < 8; ++j) {
        u0[j] = tb[ob + j][oc];  u1[j] = tb[ob + 8 + j][oc];
        v0[j] = ta[ob + j][oc];  v1[j] = ta[ob + 8 + j][oc];
    }
    *(bx8*)(At + (size_t)oc * N + ob)     = u0;
    *(bx8*)(At + (size_t)oc * N + ob + 8) = u1;
    *(bx8*)(Bt + (size_t)oc * N + ob)     = v0;
    *(bx8*)(Bt + (size_t)oc * N + ob + 8) = v1;
}

// ---------------------------------------------------------------------------
// Row softmax over 8192 bf16 logits, in place -> bf16 weights. One block/row.
// Each thread owns 32 elements; fp32 math; block reduce via shfl + LDS.
// ---------------------------------------------------------------------------
__global__ __launch_bounds__(256)
void softmax_rows(__bf16* __restrict__ W)
{
    __bf16* row = W + (size_t)blockIdx.x * MEMN;
    const int tid = threadIdx.x;
    float v[32];
#pragma unroll
    for (int i = 0; i < 4; ++i) {
        bx8 u = *(const bx8*)(row + i * 2048 + tid * 8);
#pragma unroll
        for (int j = 0; j < 8; ++j) v[i * 8 + j] = (float)u[j];
    }
    float m = -1e30f;
#pragma unroll
    for (int i = 0; i < 32; ++i) m = fmaxf(m, v[i]);
#pragma unroll
    for (int off = 32; off >= 1; off >>= 1) m = fmaxf(m, __shfl_xor(m, off, 64));
    __shared__ float red[8];
    const int wave = tid >> 6, lane = tid & 63;
    if (lane == 0) red[wave] = m;
    __syncthreads();
    m = fmaxf(fmaxf(red[0], red[1]), fmaxf(red[2], red[3]));
    float s = 0.f;
#pragma unroll
    for (int i = 0; i < 32; ++i) { v[i] = __expf(v[i] - m); s += v[i]; }
#pragma unroll
    for (int off = 32; off >= 1; off >>= 1) s += __shfl_xor(s, off, 64);
    if (lane == 0) red[4 + wave] = s;
    __syncthreads();
    s = (red[4] + red[5]) + (red[6] + red[7]);
    const float inv = 1.0f / s;
#pragma unroll
    for (int i = 0; i < 4; ++i) {
        bx8 u;
#pragma unroll
        for (int j = 0; j < 8; ++j) u[j] = (__bf16)(v[i * 8 + j] * inv);
        *(bx8*)(row + i * 2048 + tid * 8) = u;
    }
}

// ---------------------------------------------------------------------------
// NT GEMM: C[i,j] = sum_k A[i,k] * B[j,k]   (A: [M,K] row-major, B: [N,K])
// 128x128 tile, BK=32, 4 waves each computing a 64x64 sub-tile as 4x4
// mfma_f32_16x16x32_bf16 fragments. Reg-staged LDS with next-tile prefetch.
// MODE 0: bf16 out, + bias[j]   (logits)
// MODE 1: f32 out               (read_memory)
// MODE 2: f32 out, + add[idx]   (new_memory = memory + update)
// ---------------------------------------------------------------------------
template <int MODE>
__global__ __launch_bounds__(256, 2)
void gemm_nt(const __bf16* __restrict__ A, const __bf16* __restrict__ B,
             const float* __restrict__ bias, const float* __restrict__ add,
             void* __restrict__ out, int N, int K)
{
    __shared__ __bf16 As[128 * 32];
    __shared__ __bf16 Bs[128 * 32];

    const int tid  = threadIdx.x;
    const int wave = tid >> 6;
    const int lane = tid & 63;
    const int tm = blockIdx.y * 128;
    const int tn = blockIdx.x * 128;

    // staging: thread t covers 16B at flat LDS byte t*16 (row t>>2, col (t&3)*8)
    const int sr = tid >> 2;
    const int sc = (tid & 3) * 8;
    const __bf16* Ag = A + (size_t)(tm + sr) * K + sc;
    const __bf16* Bg = B + (size_t)(tn + sr) * K + sc;
    const size_t row64 = (size_t)64 * K;

    const int wr = (wave >> 1) * 64;
    const int wc = (wave & 1) * 64;
    const int fl = lane & 15;
    const int fh = lane >> 4;

    fx4 acc[4][4] = {};

    bx8 a0 = *(const bx8*)(Ag);
    bx8 a1 = *(const bx8*)(Ag + row64);
    bx8 b0 = *(const bx8*)(Bg);
    bx8 b1 = *(const bx8*)(Bg + row64);

    for (int k0 = 0; k0 < K; k0 += 32) {
        __syncthreads();
        *(bx8*)(&As[tid * 8])        = a0;
        *(bx8*)(&As[2048 + tid * 8]) = a1;
        *(bx8*)(&Bs[tid * 8])        = b0;
        *(bx8*)(&Bs[2048 + tid * 8]) = b1;
        __syncthreads();
        if (k0 + 32 < K) {           // prefetch next K-tile during compute
            Ag += 32; Bg += 32;
            a0 = *(const bx8*)(Ag);
            a1 = *(const bx8*)(Ag + row64);
            b0 = *(const bx8*)(Bg);
            b1 = *(const bx8*)(Bg + row64);
        }
        bx8 fa[4], fb[4];
#pragma unroll
        for (int mi = 0; mi < 4; ++mi)
            fa[mi] = *(const bx8*)(&As[(wr + mi * 16 + fl) * 32 + fh * 8]);
#pragma unroll
        for (int ni = 0; ni < 4; ++ni)
            fb[ni] = *(const bx8*)(&Bs[(wc + ni * 16 + fl) * 32 + fh * 8]);
#pragma unroll
        for (int mi = 0; mi < 4; ++mi)
#pragma unroll
            for (int ni = 0; ni < 4; ++ni)
                acc[mi][ni] = __builtin_amdgcn_mfma_f32_16x16x32_bf16(
                    fa[mi], fb[ni], acc[mi][ni], 0, 0, 0);
    }

    // epilogue: C/D layout col = lane&15, row = (lane>>4)*4 + reg  [m89-verified]
#pragma unroll
    for (int mi = 0; mi < 4; ++mi) {
#pragma unroll
        for (int ni = 0; ni < 4; ++ni) {
            const int gr0 = tm + wr + mi * 16 + fh * 4;
            const int gc  = tn + wc + ni * 16 + fl;
            fx4 c = acc[mi][ni];
            if (MODE == 0) {
                __bf16* O = (__bf16*)out;
                const float bv = bias[gc];
#pragma unroll
                for (int j = 0; j < 4; ++j)
                    O[(size_t)(gr0 + j) * N + gc] = (__bf16)(c[j] + bv);
            } else if (MODE == 1) {
                float* O = (float*)out;
#pragma unroll
                for (int j = 0; j < 4; ++j)
                    O[(size_t)(gr0 + j) * N + gc] = c[j];
            } else {
                float* O = (float*)out;
#pragma unroll
                for (int j = 0; j < 4; ++j) {
                    const size_t idx = (size_t)(gr0 + j) * N + gc;
                    O[idx] = c[j] + add[idx];
                }
            }
        }
    }
}

// ---------------------------------------------------------------------------
// Orchestration.
// ws layout (bytes) — 176 MiB total (was 336; suspected OOB-ws crash):
//   xb    [8192,1024] bf16  @ 0       (16 MiB)            lives whole call
//   slot1 [8192,1024] bf16  @ 16 MiB  rwb, then wwb
//   slot2 [1024,8192] bf16  @ 32 MiB  memT, then xT
//   W     [8192,8192] bf16  @ 48 MiB  (128 MiB)           logits/weights, both paths
// ---------------------------------------------------------------------------
extern "C" void kernel_launch(void* const* d_in, const int* in_sizes, int n_in,
                              void* d_out, int out_size, void* d_ws, size_t ws_size,
                              hipStream_t stream)
{
    const float* x       = (const float*)d_in[0];
    const float* memory  = (const float*)d_in[1];
    const float* read_w  = (const float*)d_in[2];
    const float* read_b  = (const float*)d_in[3];
    const float* write_w = (const float*)d_in[4];
    const float* write_b = (const float*)d_in[5];

    float* out_read = (float*)d_out;                          // [8192,1024]
    float* out_mem  = (float*)d_out + (size_t)MEMN * HID;     // [8192,1024]

    char* p = (char*)d_ws;
    const size_t MiB = 1024 * 1024;
    __bf16* xb    = (__bf16*)(p + 0 * MiB);
    __bf16* slot1 = (__bf16*)(p + 16 * MiB);   // rwb then wwb
    __bf16* slot2 = (__bf16*)(p + 32 * MiB);   // memT then xT
    __bf16* W     = (__bf16*)(p + 48 * MiB);

    // ---- read path ---------------------------------------------------------
    f32_to_bf16_vec<<<4096, 256, 0, stream>>>(x, xb);
    f32_to_bf16_vec<<<4096, 256, 0, stream>>>(read_w, slot1);
    transpose_f32_to_bf16<<<dim3(HID / 64, ROWS / 64), 256, 0, stream>>>(memory, slot2, ROWS, HID);
    // logits = x @ read_w^T + read_b  -> W (bf16)
    gemm_nt<0><<<dim3(MEMN / 128, ROWS / 128), 256, 0, stream>>>(xb, slot1, read_b, nullptr, W, MEMN, HID);
    softmax_rows<<<ROWS, 256, 0, stream>>>(W);
    // read_memory = weights @ memory = W (NT) memT
    gemm_nt<1><<<dim3(HID / 128, ROWS / 128), 256, 0, stream>>>(W, slot2, nullptr, nullptr, out_read, HID, MEMN);

    // ---- write path --------------------------------------------------------
    f32_to_bf16_vec<<<4096, 256, 0, stream>>>(write_w, slot1);
    transpose_f32_to_bf16<<<dim3(HID / 64, ROWS / 64), 256, 0, stream>>>(x, slot2, ROWS, HID);
    gemm_nt<0><<<dim3(MEMN / 128, ROWS / 128), 256, 0, stream>>>(xb, slot1, write_b, nullptr, W, MEMN, HID);
    softmax_rows<<<ROWS, 256, 0, stream>>>(W);
    // W <- W^T in place; then new_memory = W^T(NT)x^T + memory
    transpose_inplace_bf16<<<dim3(MEMN / 64, MEMN / 64), 256, 0, stream>>>(W);
    gemm_nt<2><<<dim3(HID / 128, MEMN / 128), 256, 0, stream>>>(W, slot2, nullptr, memory, out_mem, HID, ROWS);
}

// Round 3
// 752.977 us; speedup vs baseline: 1.2945x; 1.2945x over previous
//
#include <hip/hip_runtime.h>
#include <hip/hip_bf16.h>

typedef __attribute__((ext_vector_type(8))) __bf16 bx8;
typedef __attribute__((ext_vector_type(4))) float  fx4;

#define ROWS 8192   // B*S
#define HID  1024
#define MEMN 8192

// global_load_lds, 16B per lane; LDS dest = wave-uniform base + lane*16
#define GLDS(gp, lp) __builtin_amdgcn_global_load_lds( \
    (const __attribute__((address_space(1))) void*)(gp), \
    (__attribute__((address_space(3))) void*)(lp), 16, 0, 0)

// ---------------------------------------------------------------------------
// fp32 -> bf16 elementwise convert (vectorized, exact grid: n = blocks*256*8)
// ---------------------------------------------------------------------------
__global__ __launch_bounds__(256)
void f32_to_bf16_vec(const float* __restrict__ in, __bf16* __restrict__ out)
{
    const size_t i = ((size_t)blockIdx.x * 256 + threadIdx.x) * 8;
    fx4 a = *(const fx4*)(in + i);
    fx4 b = *(const fx4*)(in + i + 4);
    bx8 u;
    u[0] = (__bf16)a[0]; u[1] = (__bf16)a[1]; u[2] = (__bf16)a[2]; u[3] = (__bf16)a[3];
    u[4] = (__bf16)b[0]; u[5] = (__bf16)b[1]; u[6] = (__bf16)b[2]; u[7] = (__bf16)b[3];
    *(bx8*)(out + i) = u;
}

// ---------------------------------------------------------------------------
// fp32 [R][C] -> bf16 [C][R] transpose (64x64 tiles via LDS)
// ---------------------------------------------------------------------------
__global__ __launch_bounds__(256)
void transpose_f32_to_bf16(const float* __restrict__ in, __bf16* __restrict__ out,
                           int R, int C)
{
    __shared__ float t[64][65];
    const int tid = threadIdx.x;
    const int r0 = blockIdx.y * 64;
    const int c0 = blockIdx.x * 64;
    const int lr = tid >> 4;
    const int lc = (tid & 15) * 4;
#pragma unroll
    for (int p = 0; p < 4; ++p) {
        const int rr = p * 16 + lr;
        const fx4 v = *(const fx4*)(in + (size_t)(r0 + rr) * C + c0 + lc);
        t[rr][lc + 0] = v[0]; t[rr][lc + 1] = v[1];
        t[rr][lc + 2] = v[2]; t[rr][lc + 3] = v[3];
    }
    __syncthreads();
    const int oc = tid >> 2;
    const int ob = (tid & 3) * 16;
    bx8 u0, u1;
#pragma unroll
    for (int j = 0; j < 8; ++j) {
        u0[j] = (__bf16)t[ob + j][oc];
        u1[j] = (__bf16)t[ob + 8 + j][oc];
    }
    *(bx8*)(out + (size_t)(c0 + oc) * R + r0 + ob)     = u0;
    *(bx8*)(out + (size_t)(c0 + oc) * R + r0 + ob + 8) = u1;
}

// ---------------------------------------------------------------------------
// In-place transpose of square bf16 matrix W [MEMN][MEMN], 64x64 tile pairs.
// ---------------------------------------------------------------------------
__global__ __launch_bounds__(256)
void transpose_inplace_bf16(__bf16* __restrict__ W)
{
    const int bi = blockIdx.y;
    const int bj = blockIdx.x;
    if (bi > bj) return;
    __shared__ __bf16 ta[64][72];
    __shared__ __bf16 tb[64][72];
    const int tid = threadIdx.x;
    const int lr = tid >> 3;
    const int lc = (tid & 7) * 8;
    const size_t N = MEMN;
    __bf16* At = W + (size_t)bi * 64 * N + (size_t)bj * 64;
    __bf16* Bt = W + (size_t)bj * 64 * N + (size_t)bi * 64;
#pragma unroll
    for (int p = 0; p < 2; ++p) {
        const int rr = p * 32 + lr;
        *(bx8*)(&ta[rr][lc]) = *(const bx8*)(At + (size_t)rr * N + lc);
        *(bx8*)(&tb[rr][lc]) = *(const bx8*)(Bt + (size_t)rr * N + lc);
    }
    __syncthreads();
    const int oc = tid >> 2;
    const int ob = (tid & 3) * 16;
    bx8 u0, u1, v0, v1;
#pragma unroll
    for (int j = 0; j < 8; ++j) {
        u0[j] = tb[ob + j][oc];  u1[j] = tb[ob + 8 + j][oc];
        v0[j] = ta[ob + j][oc];  v1[j] = ta[ob + 8 + j][oc];
    }
    *(bx8*)(At + (size_t)oc * N + ob)     = u0;
    *(bx8*)(At + (size_t)oc * N + ob + 8) = u1;
    *(bx8*)(Bt + (size_t)oc * N + ob)     = v0;
    *(bx8*)(Bt + (size_t)oc * N + ob + 8) = v1;
}

// ---------------------------------------------------------------------------
// Row softmax over 8192 bf16 logits, in place. One block/row, fp32 math.
// ---------------------------------------------------------------------------
__global__ __launch_bounds__(256)
void softmax_rows(__bf16* __restrict__ W)
{
    __bf16* row = W + (size_t)blockIdx.x * MEMN;
    const int tid = threadIdx.x;
    float v[32];
#pragma unroll
    for (int i = 0; i < 4; ++i) {
        bx8 u = *(const bx8*)(row + i * 2048 + tid * 8);
#pragma unroll
        for (int j = 0; j < 8; ++j) v[i * 8 + j] = (float)u[j];
    }
    float m = -1e30f;
#pragma unroll
    for (int i = 0; i < 32; ++i) m = fmaxf(m, v[i]);
#pragma unroll
    for (int off = 32; off >= 1; off >>= 1) m = fmaxf(m, __shfl_xor(m, off, 64));
    __shared__ float red[8];
    const int wave = tid >> 6, lane = tid & 63;
    if (lane == 0) red[wave] = m;
    __syncthreads();
    m = fmaxf(fmaxf(red[0], red[1]), fmaxf(red[2], red[3]));
    float s = 0.f;
#pragma unroll
    for (int i = 0; i < 32; ++i) { v[i] = __expf(v[i] - m); s += v[i]; }
#pragma unroll
    for (int off = 32; off >= 1; off >>= 1) s += __shfl_xor(s, off, 64);
    if (lane == 0) red[4 + wave] = s;
    __syncthreads();
    s = (red[4] + red[5]) + (red[6] + red[7]);
    const float inv = 1.0f / s;
#pragma unroll
    for (int i = 0; i < 4; ++i) {
        bx8 u;
#pragma unroll
        for (int j = 0; j < 8; ++j) u[j] = (__bf16)(v[i * 8 + j] * inv);
        *(bx8*)(row + i * 2048 + tid * 8) = u;
    }
}

// ---------------------------------------------------------------------------
// NT GEMM, pipelined: C[i,j] = sum_k A[i,k]*B[j,k].
// BM x BN tile, BK=32, 512 threads = 8 waves (2Mx4N), per-wave (BM/2)x(BN/4).
// 4-deep LDS ring of (A,B) K-slices; while computing tile t (slot t&3), tile
// t+2 is staged via global_load_lds into slot (t+2)&3 (prior contents consumed
// two barriers ago -> overwrite-safe at issue). One raw s_barrier + one
// COUNTED s_waitcnt vmcnt(L) per tile (next tile's L loads stay in flight);
// vmcnt(0) only on the last tile. Bank-conflict-free via both-sides XOR
// swizzle (rule 21): linear LDS dest, source granule g^((g>>3)&3), read byte
// ^(((row>>1)&3)<<4)  -> 2 lanes/bank (free).
// MODE 0: bf16 out + bias[j]; MODE 1: f32 out; MODE 2: f32 out + add[idx].
// ---------------------------------------------------------------------------
template <int BM, int BN, int MODE>
__global__ __launch_bounds__(512)
void gemm8(const __bf16* __restrict__ A, const __bf16* __restrict__ B,
           const float* __restrict__ bias, const float* __restrict__ add,
           void* __restrict__ out, int N, int K, int nBN)
{
    constexpr int ASZ = BM * 64;      // bytes per A ring slot (BM*32*2B)
    constexpr int BSZ = BN * 64;
    constexpr int RA  = BM / 128;     // 8KB staging rounds for A slice
    constexpr int RB  = BN / 128;
    constexpr int L   = RA + RB;      // gload_lds per thread per tile
    constexpr int RWM = BM / 2, RWN = BN / 4;
    constexpr int FM  = RWM / 16, FN = RWN / 16;

    __shared__ __align__(16) char smem[4 * (ASZ + BSZ)];

    const int tid = threadIdx.x;
    const int wid = tid >> 6;
    const int ln  = tid & 63;
    const int fl  = ln & 15;
    const int fh  = ln >> 4;
    const int wr  = wid >> 2;
    const int wc  = wid & 3;

    // T1: bijective XCD swizzle (grid sizes are multiples of 8)
    const int nwg = gridDim.x;
    const int bid = blockIdx.x;
    const int wg  = (bid & 7) * (nwg >> 3) + (bid >> 3);
    const int tm  = (wg / nBN) * BM;
    const int tn  = (wg % nBN) * BN;

    const int NT = K / 32;

    // per-thread swizzled global source pointers (rule 21: source permuted,
    // LDS dest linear). granule p = R*512 + tid; row=p>>2; kg_src=(p&3)^((p>>3)&3)
    const __bf16* Ag[RA];
    const __bf16* Bg[RB];
#pragma unroll
    for (int R = 0; R < RA; ++R) {
        const int p = R * 512 + tid;
        Ag[R] = A + (size_t)(tm + (p >> 2)) * K + ((p & 3) ^ ((p >> 3) & 3)) * 8;
    }
#pragma unroll
    for (int R = 0; R < RB; ++R) {
        const int p = R * 512 + tid;
        Bg[R] = B + (size_t)(tn + (p >> 2)) * K + ((p & 3) ^ ((p >> 3) & 3)) * 8;
    }

    auto stage = [&](int t) {
        const int s = t & 3;
        const size_t ko = (size_t)t * 32;               // K element offset
        char* Ad = smem + s * ASZ + wid * 1024;
        char* Bd = smem + 4 * ASZ + s * BSZ + wid * 1024;
#pragma unroll
        for (int R = 0; R < RA; ++R) GLDS(Ag[R] + ko, Ad + R * 8192);
#pragma unroll
        for (int R = 0; R < RB; ++R) GLDS(Bg[R] + ko, Bd + R * 8192);
    };

    fx4 acc[FM][FN] = {};

    stage(0);
    if (NT > 1) stage(1);

    for (int t = 0; t < NT; ++t) {
        if (t == NT - 1) {
            asm volatile("s_waitcnt vmcnt(0)" ::: "memory");
        } else if constexpr (L == 4) {
            asm volatile("s_waitcnt vmcnt(4)" ::: "memory");
        } else {
            asm volatile("s_waitcnt vmcnt(3)" ::: "memory");
        }
        __builtin_amdgcn_s_barrier();
        asm volatile("" ::: "memory");
        if (t + 2 < NT) stage(t + 2);

        const char* Ab = smem + (t & 3) * ASZ;
        const char* Bb = smem + 4 * ASZ + (t & 3) * BSZ;
        bx8 fa[FM], fb[FN];
#pragma unroll
        for (int mi = 0; mi < FM; ++mi) {
            const int r = wr * RWM + mi * 16 + fl;
            fa[mi] = *(const bx8*)(Ab + r * 64 + ((fh ^ ((r >> 1) & 3)) << 4));
        }
#pragma unroll
        for (int ni = 0; ni < FN; ++ni) {
            const int c = wc * RWN + ni * 16 + fl;
            fb[ni] = *(const bx8*)(Bb + c * 64 + ((fh ^ ((c >> 1) & 3)) << 4));
        }
        __builtin_amdgcn_s_setprio(1);
#pragma unroll
        for (int mi = 0; mi < FM; ++mi)
#pragma unroll
            for (int ni = 0; ni < FN; ++ni)
                acc[mi][ni] = __builtin_amdgcn_mfma_f32_16x16x32_bf16(
                    fa[mi], fb[ni], acc[mi][ni], 0, 0, 0);
        __builtin_amdgcn_s_setprio(0);
    }

    // epilogue: C/D layout col = lane&15, row = (lane>>4)*4 + reg
#pragma unroll
    for (int mi = 0; mi < FM; ++mi) {
#pragma unroll
        for (int ni = 0; ni < FN; ++ni) {
            const int gr0 = tm + wr * RWM + mi * 16 + fh * 4;
            const int gc  = tn + wc * RWN + ni * 16 + fl;
            fx4 c = acc[mi][ni];
            if constexpr (MODE == 0) {
                __bf16* O = (__bf16*)out;
                const float bv = bias[gc];
#pragma unroll
                for (int j = 0; j < 4; ++j)
                    O[(size_t)(gr0 + j) * N + gc] = (__bf16)(c[j] + bv);
            } else if constexpr (MODE == 1) {
                float* O = (float*)out;
#pragma unroll
                for (int j = 0; j < 4; ++j)
                    O[(size_t)(gr0 + j) * N + gc] = c[j];
            } else {
                float* O = (float*)out;
#pragma unroll
                for (int j = 0; j < 4; ++j) {
                    const size_t idx = (size_t)(gr0 + j) * N + gc;
                    O[idx] = c[j] + add[idx];
                }
            }
        }
    }
}

// ---------------------------------------------------------------------------
// Orchestration. ws layout (176 MiB):
//   xb    [8192,1024] bf16  @ 0
//   slot1 [8192,1024] bf16  @ 16 MiB  (rwb then wwb)
//   slot2 [1024,8192] bf16  @ 32 MiB  (memT then xT)
//   W     [8192,8192] bf16  @ 48 MiB
// ---------------------------------------------------------------------------
extern "C" void kernel_launch(void* const* d_in, const int* in_sizes, int n_in,
                              void* d_out, int out_size, void* d_ws, size_t ws_size,
                              hipStream_t stream)
{
    const float* x       = (const float*)d_in[0];
    const float* memory  = (const float*)d_in[1];
    const float* read_w  = (const float*)d_in[2];
    const float* read_b  = (const float*)d_in[3];
    const float* write_w = (const float*)d_in[4];
    const float* write_b = (const float*)d_in[5];

    float* out_read = (float*)d_out;
    float* out_mem  = (float*)d_out + (size_t)MEMN * HID;

    char* p = (char*)d_ws;
    const size_t MiB = 1024 * 1024;
    __bf16* xb    = (__bf16*)(p + 0 * MiB);
    __bf16* slot1 = (__bf16*)(p + 16 * MiB);
    __bf16* slot2 = (__bf16*)(p + 32 * MiB);
    __bf16* W     = (__bf16*)(p + 48 * MiB);

    // ---- read path ---------------------------------------------------------
    f32_to_bf16_vec<<<4096, 256, 0, stream>>>(x, xb);
    f32_to_bf16_vec<<<4096, 256, 0, stream>>>(read_w, slot1);
    transpose_f32_to_bf16<<<dim3(HID / 64, ROWS / 64), 256, 0, stream>>>(memory, slot2, ROWS, HID);
    gemm8<256, 256, 0><<<(ROWS / 256) * (MEMN / 256), 512, 0, stream>>>(
        xb, slot1, read_b, nullptr, W, MEMN, HID, MEMN / 256);
    softmax_rows<<<ROWS, 256, 0, stream>>>(W);
    gemm8<128, 256, 1><<<(ROWS / 128) * (HID / 256), 512, 0, stream>>>(
        W, slot2, nullptr, nullptr, out_read, HID, MEMN, HID / 256);

    // ---- write path --------------------------------------------------------
    f32_to_bf16_vec<<<4096, 256, 0, stream>>>(write_w, slot1);
    transpose_f32_to_bf16<<<dim3(HID / 64, ROWS / 64), 256, 0, stream>>>(x, slot2, ROWS, HID);
    gemm8<256, 256, 0><<<(ROWS / 256) * (MEMN / 256), 512, 0, stream>>>(
        xb, slot1, write_b, nullptr, W, MEMN, HID, MEMN / 256);
    softmax_rows<<<ROWS, 256, 0, stream>>>(W);
    transpose_inplace_bf16<<<dim3(MEMN / 64, MEMN / 64), 256, 0, stream>>>(W);
    gemm8<128, 256, 2><<<(MEMN / 128) * (HID / 256), 512, 0, stream>>>(
        W, slot2, nullptr, memory, out_mem, HID, ROWS, HID / 256);
}